// Round 2
// baseline (500.077 us; speedup 1.0000x reference)
//
#include <hip/hip_runtime.h>

#define NB 4
#define NH 16
#define NS 4096
#define ND 64
#define NBH (NB * NH)
#define EPSF 1e-6f

__device__ __forceinline__ float phi_f(float x) {
    // elu(x)+1 : x>0 ? x+1 : exp(x)
    return x > 0.0f ? x + 1.0f : __expf(x);
}

// =====================================================================
// Pass 1: KV[bh] = phiK^T @ V (64x64), K1[bh] = colsum(phiK)
// 1-wave blocks, 8x8 register tile per lane (1 B LDS / FMA), 32-row LDS
// tiles (16 KB -> 10 blocks/CU), rolling register prefetch of next tile.
// =====================================================================
#define P1_TILE 32
#define P1_CHUNK 128

__global__ __launch_bounds__(64)
void la_pass1(const float* __restrict__ Kin, const float* __restrict__ Vin,
              const float* __restrict__ Min, float* __restrict__ KV,
              float* __restrict__ K1)
{
    const int t  = threadIdx.x;              // 0..63
    const int bh = blockIdx.y;
    const int bb = bh >> 4;                  // H = 16
    const long long base = (long long)bh * NS * ND;
    const float* Kb = Kin + base;
    const float* Vb = Vin + base;
    const float* Mb = Min + (long long)bb * NS;

    __shared__ float sk[P1_TILE * ND];       // 8 KB
    __shared__ float sv[P1_TILE * ND];       // 8 KB

    const int d0 = (t >> 3) * 8;             // this lane's 8 d-rows
    const int v0 = (t & 7) * 8;              // this lane's 8 v-cols

    float acc[8][8];
    #pragma unroll
    for (int i = 0; i < 8; ++i)
        #pragma unroll
        for (int j = 0; j < 8; ++j) acc[i][j] = 0.0f;
    float acc1[8];
    #pragma unroll
    for (int i = 0; i < 8; ++i) acc1[i] = 0.0f;

    const int s0 = blockIdx.x * P1_CHUNK;

    // rolling prefetch registers (tile 0)
    float4 kreg[8], vreg[8];
    float  mreg[8];
    #pragma unroll
    for (int i = 0; i < 8; ++i) {
        const int f = t + 64 * i;            // float4 index 0..511
        const int r = f >> 4;                // 0..31
        const int c = (f & 15) * 4;
        const long long gr = (long long)(s0 + r) * ND + c;
        kreg[i] = *(const float4*)(Kb + gr);
        vreg[i] = *(const float4*)(Vb + gr);
        mreg[i] = Mb[s0 + r];
    }

    for (int tile = 0; tile < P1_CHUNK / P1_TILE; ++tile) {
        __syncthreads();                     // previous tile's reads done
        const int nt0 = s0 + (tile + 1) * P1_TILE;
        #pragma unroll
        for (int i = 0; i < 8; ++i) {
            const int f = t + 64 * i;
            float4 pk;
            pk.x = phi_f(kreg[i].x) * mreg[i];
            pk.y = phi_f(kreg[i].y) * mreg[i];
            pk.z = phi_f(kreg[i].z) * mreg[i];
            pk.w = phi_f(kreg[i].w) * mreg[i];
            *(float4*)(sk + f * 4) = pk;     // flat: lane-consecutive, conflict-free
            *(float4*)(sv + f * 4) = vreg[i];
            if (tile < P1_CHUNK / P1_TILE - 1) {
                const int r = f >> 4;
                const int c = (f & 15) * 4;
                const long long gr = (long long)(nt0 + r) * ND + c;
                kreg[i] = *(const float4*)(Kb + gr);
                vreg[i] = *(const float4*)(Vb + gr);
                mreg[i] = Mb[nt0 + r];
            }
        }
        __syncthreads();
        #pragma unroll 4
        for (int r = 0; r < P1_TILE; ++r) {
            const float4 a0 = *(const float4*)(sk + r * ND + d0);
            const float4 a1 = *(const float4*)(sk + r * ND + d0 + 4);
            const float4 b0 = *(const float4*)(sv + r * ND + v0);
            const float4 b1 = *(const float4*)(sv + r * ND + v0 + 4);
            const float av[8] = {a0.x, a0.y, a0.z, a0.w, a1.x, a1.y, a1.z, a1.w};
            const float bv[8] = {b0.x, b0.y, b0.z, b0.w, b1.x, b1.y, b1.z, b1.w};
            #pragma unroll
            for (int i = 0; i < 8; ++i) {
                acc1[i] += av[i];
                #pragma unroll
                for (int j = 0; j < 8; ++j)
                    acc[i][j] += av[i] * bv[j];
            }
        }
    }

    float* kvb = KV + (long long)bh * ND * ND;
    #pragma unroll
    for (int i = 0; i < 8; ++i)
        #pragma unroll
        for (int j = 0; j < 8; ++j)
            atomicAdd(&kvb[(d0 + i) * ND + v0 + j], acc[i][j]);
    if ((t & 7) == 0) {
        float* k1b = K1 + bh * ND;
        #pragma unroll
        for (int i = 0; i < 8; ++i) atomicAdd(&k1b[d0 + i], acc1[i]);
    }
}

// =====================================================================
// Pass 2: out = (phiQ @ KV) / (phiQ . k1 + eps)
// 1-wave blocks, 64 rows/block, 8x8 register tile per lane.
// Q staged transposed (sqT[d][r], row stride 68 -> conflict-free b128
// reads for 8-row lane groups) via a padded 16x65 bounce buffer.
// LDS 38.2 KB -> 4 blocks/CU.
// =====================================================================
#define P2_ROWS 64
#define SQT_LD 68

__global__ __launch_bounds__(64)
void la_pass2(const float* __restrict__ Qin, const float* __restrict__ KV,
              const float* __restrict__ K1, float* __restrict__ Out)
{
    const int t  = threadIdx.x;              // 0..63
    const int bh = blockIdx.y;
    const int s0 = blockIdx.x * P2_ROWS;
    const long long base = (long long)bh * NS * ND;

    __shared__ float skv[ND * ND];           // 16 KB
    __shared__ float sqT[ND * SQT_LD];       // 17 KB, sqT[d*68 + r] = phi(q[r][d]/8)
    __shared__ float stmp[16 * 65];          // 4.06 KB bounce for transpose
    __shared__ float sk1[ND];

    // ---- issue ALL global loads up front (32+ outstanding) ----
    float4 qld[16];                          // 4 quarters x 4
    #pragma unroll
    for (int q = 0; q < 4; ++q)
        #pragma unroll
        for (int i = 0; i < 4; ++i) {
            const int f = t + 64 * i;        // 0..255
            const int r = f >> 4;            // 0..15
            const int c = (f & 15) * 4;
            qld[q * 4 + i] = *(const float4*)(Qin + base + (long long)(s0 + 16 * q + r) * ND + c);
        }
    float4 kvld[16];
    {
        const float4* src = (const float4*)(KV + (long long)bh * ND * ND);
        #pragma unroll
        for (int i = 0; i < 16; ++i) kvld[i] = src[t + 64 * i];
    }
    float4 k1ld;
    if (t < 16) k1ld = ((const float4*)(K1 + bh * ND))[t];

    // ---- stage KV + k1 ----
    {
        float4* dst = (float4*)skv;
        #pragma unroll
        for (int i = 0; i < 16; ++i) dst[t + 64 * i] = kvld[i];
        if (t < 16) ((float4*)sk1)[t] = k1ld;
    }

    // ---- stage Q transposed, 4 quarters of 16 rows ----
    for (int q = 0; q < 4; ++q) {
        __syncthreads();                     // protect stmp from prev quarter
        #pragma unroll
        for (int i = 0; i < 4; ++i) {
            const int f = t + 64 * i;
            const int r = f >> 4;
            const int c = (f & 15) * 4;
            const float4 v = qld[q * 4 + i];
            stmp[r * 65 + c + 0] = phi_f(v.x * 0.125f);
            stmp[r * 65 + c + 1] = phi_f(v.y * 0.125f);
            stmp[r * 65 + c + 2] = phi_f(v.z * 0.125f);
            stmp[r * 65 + c + 3] = phi_f(v.w * 0.125f);
        }
        __syncthreads();
        // transpose: lane t owns column (d-index) t; reads are (rr+t)%32 banks -> free
        float vals[16];
        #pragma unroll
        for (int rr = 0; rr < 16; ++rr) vals[rr] = stmp[rr * 65 + t];
        #pragma unroll
        for (int j = 0; j < 4; ++j) {
            float4 w;
            w.x = vals[4 * j + 0]; w.y = vals[4 * j + 1];
            w.z = vals[4 * j + 2]; w.w = vals[4 * j + 3];
            *(float4*)(sqT + t * SQT_LD + 16 * q + 4 * j) = w;
        }
    }
    __syncthreads();

    // ---- main loop: 8x8 per lane over d ----
    const int r0 = (t >> 3) * 8;
    const int v0 = (t & 7) * 8;

    float acc[8][8];
    #pragma unroll
    for (int i = 0; i < 8; ++i)
        #pragma unroll
        for (int j = 0; j < 8; ++j) acc[i][j] = 0.0f;
    float nacc[8];
    #pragma unroll
    for (int i = 0; i < 8; ++i) nacc[i] = 0.0f;

    for (int d = 0; d < ND; d += 4) {
        const float4 s1 = *(const float4*)(sk1 + d);
        const float s1v[4] = {s1.x, s1.y, s1.z, s1.w};
        #pragma unroll
        for (int k = 0; k < 4; ++k) {
            const float4 q0 = *(const float4*)(sqT + (d + k) * SQT_LD + r0);
            const float4 q1 = *(const float4*)(sqT + (d + k) * SQT_LD + r0 + 4);
            const float4 b0 = *(const float4*)(skv + (d + k) * ND + v0);
            const float4 b1 = *(const float4*)(skv + (d + k) * ND + v0 + 4);
            const float qv[8] = {q0.x, q0.y, q0.z, q0.w, q1.x, q1.y, q1.z, q1.w};
            const float bv[8] = {b0.x, b0.y, b0.z, b0.w, b1.x, b1.y, b1.z, b1.w};
            #pragma unroll
            for (int i = 0; i < 8; ++i) {
                nacc[i] += qv[i] * s1v[k];
                #pragma unroll
                for (int j = 0; j < 8; ++j)
                    acc[i][j] += qv[i] * bv[j];
            }
        }
    }

    // ---- epilogue ----
    float* outb = Out + base;
    #pragma unroll
    for (int i = 0; i < 8; ++i) {
        const float rn = 1.0f / (nacc[i] + EPSF);
        float4 o0, o1;
        o0.x = acc[i][0] * rn; o0.y = acc[i][1] * rn;
        o0.z = acc[i][2] * rn; o0.w = acc[i][3] * rn;
        o1.x = acc[i][4] * rn; o1.y = acc[i][5] * rn;
        o1.z = acc[i][6] * rn; o1.w = acc[i][7] * rn;
        *(float4*)(outb + (long long)(s0 + r0 + i) * ND + v0)     = o0;
        *(float4*)(outb + (long long)(s0 + r0 + i) * ND + v0 + 4) = o1;
    }
}

extern "C" void kernel_launch(void* const* d_in, const int* in_sizes, int n_in,
                              void* d_out, int out_size, void* d_ws, size_t ws_size,
                              hipStream_t stream)
{
    const float* Q = (const float*)d_in[0];
    const float* K = (const float*)d_in[1];
    const float* V = (const float*)d_in[2];
    const float* M = (const float*)d_in[3];
    float* Out = (float*)d_out;

    float* KV = (float*)d_ws;                          // [NBH][64][64]
    float* K1 = KV + (size_t)NBH * ND * ND;            // [NBH][64]

    const size_t zbytes = ((size_t)NBH * ND * ND + (size_t)NBH * ND) * sizeof(float);
    hipMemsetAsync(d_ws, 0, zbytes, stream);

    dim3 g1(NS / P1_CHUNK, NBH);                       // (32, 64)
    la_pass1<<<g1, dim3(64), 0, stream>>>(K, V, M, KV, K1);

    dim3 g2(NS / P2_ROWS, NBH);                        // (64, 64)
    la_pass2<<<g2, dim3(64), 0, stream>>>(Q, KV, K1, Out);
}

// Round 3
// 473.128 us; speedup vs baseline: 1.0570x; 1.0570x over previous
//
#include <hip/hip_runtime.h>

#define NB 4
#define NH 16
#define NS 4096
#define ND 64
#define NBH (NB * NH)
#define EPSF 1e-6f

__device__ __forceinline__ float phi_f(float x) {
    // elu(x)+1 : x>0 ? x+1 : exp(x)
    return x > 0.0f ? x + 1.0f : __expf(x);
}

// =====================================================================
// Pass 1: KV[bh] = phiK^T @ V (64x64), K1[bh] = colsum(phiK)
// 1-wave blocks, 8x8 register tile/lane (4 ds_read_b128 per 64 FMA).
// Staging in 4-float4 sub-batches => low live-register count (no spill).
// k1 accumulated during staging (lane owns fixed column group c0).
// LDS 16 KB; grid (32,64) = 2048 blocks = 8 blocks/CU.
// =====================================================================
#define P1_CHUNK 128
#define P1_TILE 32

__global__ __launch_bounds__(64, 2)
void la_pass1(const float* __restrict__ Kin, const float* __restrict__ Vin,
              const float* __restrict__ Min, float* __restrict__ KV,
              float* __restrict__ K1)
{
    const int t  = threadIdx.x;              // 0..63
    const int bh = blockIdx.y;
    const int bb = bh >> 4;                  // H = 16
    const long long base = (long long)bh * NS * ND;
    const float* Kb = Kin + base;
    const float* Vb = Vin + base;
    const float* Mb = Min + (long long)bb * NS;

    __shared__ float sk[P1_TILE * ND];       // 8 KB  phi(K)*mask tile
    __shared__ float sv[P1_TILE * ND];       // 8 KB  V tile

    const int d0 = (t >> 3) * 8;             // lane's 8 d-rows
    const int v0 = (t & 7) * 8;              // lane's 8 v-cols
    const int c0 = (t & 15) * 4;             // lane's fixed staging column group
    const int rr = t >> 4;                   // staging row within group

    float acc[8][8];
    #pragma unroll
    for (int i = 0; i < 8; ++i)
        #pragma unroll
        for (int j = 0; j < 8; ++j) acc[i][j] = 0.0f;
    float k1p[4] = {0.f, 0.f, 0.f, 0.f};

    const int s0 = blockIdx.x * P1_CHUNK;

    for (int tile = 0; tile < P1_CHUNK; tile += P1_TILE) {
        const int rbase = s0 + tile;
        __syncthreads();                     // previous tile fully consumed
        #pragma unroll
        for (int hb = 0; hb < 2; ++hb) {     // two sub-batches of 4 float4
            float4 kr[4], vr[4];
            float  mr[4];
            #pragma unroll
            for (int i = 0; i < 4; ++i) {
                const int r = rr + 16 * hb + 4 * i;     // 0..31
                const long long g = (long long)(rbase + r) * ND + c0;
                kr[i] = *(const float4*)(Kb + g);
                vr[i] = *(const float4*)(Vb + g);
                mr[i] = Mb[rbase + r];
            }
            #pragma unroll
            for (int i = 0; i < 4; ++i) {
                const int r = rr + 16 * hb + 4 * i;
                float4 pk;
                pk.x = phi_f(kr[i].x) * mr[i];
                pk.y = phi_f(kr[i].y) * mr[i];
                pk.z = phi_f(kr[i].z) * mr[i];
                pk.w = phi_f(kr[i].w) * mr[i];
                k1p[0] += pk.x; k1p[1] += pk.y;
                k1p[2] += pk.z; k1p[3] += pk.w;
                *(float4*)(sk + r * ND + c0) = pk;
                *(float4*)(sv + r * ND + c0) = vr[i];
            }
        }
        __syncthreads();
        #pragma unroll 4
        for (int r = 0; r < P1_TILE; ++r) {
            const float4 a0 = *(const float4*)(sk + r * ND + d0);
            const float4 a1 = *(const float4*)(sk + r * ND + d0 + 4);
            const float4 b0 = *(const float4*)(sv + r * ND + v0);
            const float4 b1 = *(const float4*)(sv + r * ND + v0 + 4);
            const float av[8] = {a0.x, a0.y, a0.z, a0.w, a1.x, a1.y, a1.z, a1.w};
            const float bv[8] = {b0.x, b0.y, b0.z, b0.w, b1.x, b1.y, b1.z, b1.w};
            #pragma unroll
            for (int i = 0; i < 8; ++i)
                #pragma unroll
                for (int j = 0; j < 8; ++j)
                    acc[i][j] += av[i] * bv[j];
        }
    }

    float* kvb = KV + (long long)bh * ND * ND;
    #pragma unroll
    for (int i = 0; i < 8; ++i)
        #pragma unroll
        for (int j = 0; j < 8; ++j)
            atomicAdd(&kvb[(d0 + i) * ND + v0 + j], acc[i][j]);
    float* k1b = K1 + bh * ND;
    #pragma unroll
    for (int j = 0; j < 4; ++j)
        atomicAdd(&k1b[c0 + j], k1p[j]);     // 4 lanes share c0 -> atomics combine
}

// =====================================================================
// Pass 2: out = (phiQ @ KV) / (phiQ . k1 + eps)
// 1-wave blocks, 64 rows x 64 cols, 8x8 tile/lane, d processed in two
// 32-wide halves so LDS = 8 KB (KV half) + 8.7 KB (transposed phiQ half)
// => ~17 KB => 9 blocks/CU. Transposed Q gives b128 fragment reads.
// =====================================================================
#define SQT_LD 68

__global__ __launch_bounds__(64, 2)
void la_pass2(const float* __restrict__ Qin, const float* __restrict__ KV,
              const float* __restrict__ K1, float* __restrict__ Out)
{
    const int t  = threadIdx.x;              // 0..63
    const int bh = blockIdx.y;
    const int s0 = blockIdx.x * 64;
    const long long base = (long long)bh * NS * ND;

    __shared__ float skv[32 * ND];           // 8 KB: current d-half of KV
    __shared__ float sqT[32 * SQT_LD];       // 8.7 KB: sqT[dd][r] = phi(q[r][d]/8)
    __shared__ float sk1[ND];

    const int r0 = (t >> 3) * 8;             // lane's 8 rows
    const int v0 = (t & 7) * 8;              // lane's 8 cols

    float acc[8][8];
    #pragma unroll
    for (int i = 0; i < 8; ++i)
        #pragma unroll
        for (int j = 0; j < 8; ++j) acc[i][j] = 0.0f;
    float nacc[8];
    #pragma unroll
    for (int i = 0; i < 8; ++i) nacc[i] = 0.0f;

    if (t < 16)
        ((float4*)sk1)[t] = ((const float4*)(K1 + bh * ND))[t];

    for (int half = 0; half < 2; ++half) {
        const int dbase = half * 32;
        __syncthreads();                     // prior half consumed; sk1 visible
        // ---- stage KV half (rows dbase..dbase+31, contiguous) ----
        {
            const float4* src = (const float4*)(KV + (long long)bh * ND * ND + dbase * ND);
            float4* dst = (float4*)skv;
            #pragma unroll
            for (int hb = 0; hb < 2; ++hb) {
                float4 kvv[4];
                #pragma unroll
                for (int i = 0; i < 4; ++i) kvv[i] = src[t + 64 * (4 * hb + i)];
                #pragma unroll
                for (int i = 0; i < 4; ++i) dst[t + 64 * (4 * hb + i)] = kvv[i];
            }
        }
        // ---- stage phi(Q) half, transposed ----
        {
            const int c = (t & 7) * 4;       // fixed col group within half
            #pragma unroll
            for (int hb = 0; hb < 2; ++hb) {
                float4 q4[4];
                #pragma unroll
                for (int i = 0; i < 4; ++i) {
                    const int r = (t >> 3) + 8 * (4 * hb + i);   // 0..63
                    q4[i] = *(const float4*)(Qin + base + (long long)(s0 + r) * ND + dbase + c);
                }
                #pragma unroll
                for (int i = 0; i < 4; ++i) {
                    const int r = (t >> 3) + 8 * (4 * hb + i);
                    sqT[(c + 0) * SQT_LD + r] = phi_f(q4[i].x * 0.125f);
                    sqT[(c + 1) * SQT_LD + r] = phi_f(q4[i].y * 0.125f);
                    sqT[(c + 2) * SQT_LD + r] = phi_f(q4[i].z * 0.125f);
                    sqT[(c + 3) * SQT_LD + r] = phi_f(q4[i].w * 0.125f);
                }
            }
        }
        __syncthreads();
        // ---- main loop over this d-half ----
        #pragma unroll 4
        for (int dd = 0; dd < 32; ++dd) {
            const float4 a0 = *(const float4*)(sqT + dd * SQT_LD + r0);
            const float4 a1 = *(const float4*)(sqT + dd * SQT_LD + r0 + 4);
            const float4 b0 = *(const float4*)(skv + dd * ND + v0);
            const float4 b1 = *(const float4*)(skv + dd * ND + v0 + 4);
            const float s1 = sk1[dbase + dd];
            const float qv[8] = {a0.x, a0.y, a0.z, a0.w, a1.x, a1.y, a1.z, a1.w};
            const float bv[8] = {b0.x, b0.y, b0.z, b0.w, b1.x, b1.y, b1.z, b1.w};
            #pragma unroll
            for (int i = 0; i < 8; ++i) {
                nacc[i] += qv[i] * s1;
                #pragma unroll
                for (int j = 0; j < 8; ++j)
                    acc[i][j] += qv[i] * bv[j];
            }
        }
    }

    float* outb = Out + base;
    #pragma unroll
    for (int i = 0; i < 8; ++i) {
        const float rn = 1.0f / (nacc[i] + EPSF);
        float4 o0, o1;
        o0.x = acc[i][0] * rn; o0.y = acc[i][1] * rn;
        o0.z = acc[i][2] * rn; o0.w = acc[i][3] * rn;
        o1.x = acc[i][4] * rn; o1.y = acc[i][5] * rn;
        o1.z = acc[i][6] * rn; o1.w = acc[i][7] * rn;
        *(float4*)(outb + (long long)(s0 + r0 + i) * ND + v0)     = o0;
        *(float4*)(outb + (long long)(s0 + r0 + i) * ND + v0 + 4) = o1;
    }
}

extern "C" void kernel_launch(void* const* d_in, const int* in_sizes, int n_in,
                              void* d_out, int out_size, void* d_ws, size_t ws_size,
                              hipStream_t stream)
{
    const float* Q = (const float*)d_in[0];
    const float* K = (const float*)d_in[1];
    const float* V = (const float*)d_in[2];
    const float* M = (const float*)d_in[3];
    float* Out = (float*)d_out;

    float* KV = (float*)d_ws;                          // [NBH][64][64]
    float* K1 = KV + (size_t)NBH * ND * ND;            // [NBH][64]

    const size_t zbytes = ((size_t)NBH * ND * ND + (size_t)NBH * ND) * sizeof(float);
    hipMemsetAsync(d_ws, 0, zbytes, stream);

    dim3 g1(NS / P1_CHUNK, NBH);                       // (32, 64)
    la_pass1<<<g1, dim3(64), 0, stream>>>(K, V, M, KV, K1);

    dim3 g2(NS / 64, NBH);                             // (64, 64)
    la_pass2<<<g2, dim3(64), 0, stream>>>(Q, KV, K1, Out);
}

// Round 4
// 263.859 us; speedup vs baseline: 1.8952x; 1.7931x over previous
//
#include <hip/hip_runtime.h>

#define NB 4
#define NH 16
#define NS 4096
#define ND 64
#define NBH (NB * NH)
#define EPSF 1e-6f

#define P1_CHUNKS 16
#define P1_ROWS (NS / P1_CHUNKS)   // 256 rows per pass1 block
#define P2_ROWS 128

__device__ __forceinline__ float phi_f(float x) {
    // elu(x)+1 : x>0 ? x+1 : exp(x)
    return x > 0.0f ? x + 1.0f : __expf(x);
}

// =====================================================================
// Pass 1: partial KV = phiK^T @ V over a 256-row chunk, plus partial k1.
// 256 threads, 4x4 tile/lane (VGPR-light, broadcast-heavy LDS reads),
// 64-row LDS tiles with register prefetch of the next tile.
// PART=true: plain coalesced stores to per-chunk partial buffers.
// PART=false: coalesced (lane-contiguous) atomicAdd fallback.
// =====================================================================
template<bool PART>
__global__ __launch_bounds__(256, 2)
void la_pass1(const float* __restrict__ Kin, const float* __restrict__ Vin,
              const float* __restrict__ Min, float* __restrict__ okv,
              float* __restrict__ ok1)
{
    const int t  = threadIdx.x;
    const int cx = blockIdx.x;
    const int bh = blockIdx.y;
    const int bb = bh >> 4;                  // H = 16
    const long long base = (long long)bh * NS * ND;
    const float* Kb = Kin + base;
    const float* Vb = Vin + base;
    const float* Mb = Min + (long long)bb * NS;

    __shared__ float sk[64 * ND];            // 16 KB phi(K)*mask tile
    __shared__ float sv[64 * ND];            // 16 KB V tile

    const int lrow = t >> 4;                 // 0..15 loader row group
    const int lcol = (t & 15) * 4;           // 0..60 loader col
    const int d0 = (t >> 4) * 4;             // lane's 4 d-rows
    const int v0 = (t & 15) * 4;             // lane's 4 v-cols

    float acc[4][4] = {};
    float k1p[4] = {0.f, 0.f, 0.f, 0.f};     // lane's partial colsum for lcol..lcol+3

    const int s0 = cx * P1_ROWS;

    // prefetch tile 0 into registers
    float4 kr[4], vr[4];
    float  mr[4];
    #pragma unroll
    for (int i = 0; i < 4; ++i) {
        const int r = lrow + 16 * i;
        const long long g = (long long)(s0 + r) * ND + lcol;
        kr[i] = *(const float4*)(Kb + g);
        vr[i] = *(const float4*)(Vb + g);
        mr[i] = Mb[s0 + r];
    }

    for (int tile = 0; tile < P1_ROWS; tile += 64) {
        __syncthreads();                     // previous tile fully consumed
        #pragma unroll
        for (int i = 0; i < 4; ++i) {
            const int r = lrow + 16 * i;
            float4 pk;
            pk.x = phi_f(kr[i].x) * mr[i];
            pk.y = phi_f(kr[i].y) * mr[i];
            pk.z = phi_f(kr[i].z) * mr[i];
            pk.w = phi_f(kr[i].w) * mr[i];
            k1p[0] += pk.x; k1p[1] += pk.y;
            k1p[2] += pk.z; k1p[3] += pk.w;
            *(float4*)(sk + r * ND + lcol) = pk;
            *(float4*)(sv + r * ND + lcol) = vr[i];
        }
        if (tile + 64 < P1_ROWS) {           // prefetch next tile
            const int nb = s0 + tile + 64;
            #pragma unroll
            for (int i = 0; i < 4; ++i) {
                const int r = lrow + 16 * i;
                const long long g = (long long)(nb + r) * ND + lcol;
                kr[i] = *(const float4*)(Kb + g);
                vr[i] = *(const float4*)(Vb + g);
                mr[i] = Mb[nb + r];
            }
        }
        __syncthreads();
        #pragma unroll 4
        for (int r = 0; r < 64; ++r) {
            const float4 a = *(const float4*)(sk + r * ND + d0);   // 16-lane broadcast
            const float4 b = *(const float4*)(sv + r * ND + v0);   // 4-lane broadcast
            const float av[4] = {a.x, a.y, a.z, a.w};
            const float bv[4] = {b.x, b.y, b.z, b.w};
            #pragma unroll
            for (int i = 0; i < 4; ++i)
                #pragma unroll
                for (int j = 0; j < 4; ++j)
                    acc[i][j] += av[i] * bv[j];
        }
    }

    // stage results through LDS so global writes are lane-contiguous
    __syncthreads();
    #pragma unroll
    for (int i = 0; i < 4; ++i)
        #pragma unroll
        for (int j = 0; j < 4; ++j)
            sk[(d0 + i) * ND + v0 + j] = acc[i][j];
    #pragma unroll
    for (int c = 0; c < 4; ++c)
        sv[lrow * ND + lcol + c] = k1p[c];   // k1 partials, group-major [16][64]
    __syncthreads();

    if (PART) {
        float* pkv = okv + (long long)(bh * P1_CHUNKS + cx) * (ND * ND);
        #pragma unroll
        for (int i = 0; i < 4; ++i)
            ((float4*)pkv)[t + 256 * i] = ((const float4*)sk)[t + 256 * i];
        if (t < ND) {
            float s = 0.f;
            #pragma unroll
            for (int g = 0; g < 16; ++g) s += sv[g * ND + t];
            ok1[(bh * P1_CHUNKS + cx) * ND + t] = s;
        }
    } else {
        float* kvb = okv + (long long)bh * ND * ND;
        #pragma unroll
        for (int i = 0; i < 16; ++i)
            atomicAdd(&kvb[t + 256 * i], sk[t + 256 * i]);  // 1 KB contiguous per inst
        if (t < ND) {
            float s = 0.f;
            #pragma unroll
            for (int g = 0; g < 16; ++g) s += sv[g * ND + t];
            atomicAdd(&ok1[bh * ND + t], s);
        }
    }
}

// =====================================================================
// Reduce: KV[bh] = sum of 16 partial tiles; K1[bh] = sum of partial k1.
// 64 blocks x 256 threads; ~17 MB read (L2/L3-hot), 1 MB write.
// =====================================================================
__global__ __launch_bounds__(256)
void la_reduce(const float* __restrict__ pkv, const float* __restrict__ pk1,
               float* __restrict__ kv, float* __restrict__ k1)
{
    const int t = threadIdx.x;
    const int bh = blockIdx.x;
    const float4* src = (const float4*)(pkv + (long long)bh * P1_CHUNKS * ND * ND);
    float4 a[4];
    #pragma unroll
    for (int i = 0; i < 4; ++i) { a[i].x = 0.f; a[i].y = 0.f; a[i].z = 0.f; a[i].w = 0.f; }
    for (int c = 0; c < P1_CHUNKS; ++c) {
        #pragma unroll
        for (int i = 0; i < 4; ++i) {
            const float4 v = src[c * 1024 + t + 256 * i];
            a[i].x += v.x; a[i].y += v.y; a[i].z += v.z; a[i].w += v.w;
        }
    }
    float4* dst = (float4*)(kv + (long long)bh * ND * ND);
    #pragma unroll
    for (int i = 0; i < 4; ++i) dst[t + 256 * i] = a[i];
    if (t < ND) {
        float s = 0.f;
        for (int c = 0; c < P1_CHUNKS; ++c) s += pk1[(bh * P1_CHUNKS + c) * ND + t];
        k1[bh * ND + t] = s;
    }
}

// =====================================================================
// Pass 2: out = (phiQ @ KV) / (phiQ . k1 + eps)
// 256 threads, 128 rows/block, 4x8 tile/lane, normalizer fused into
// the main loop. sq padded to 65 -> conflict-free; KV reads broadcast.
// =====================================================================
__global__ __launch_bounds__(256, 2)
void la_pass2(const float* __restrict__ Qin, const float* __restrict__ KV,
              const float* __restrict__ K1, float* __restrict__ Out)
{
    const int t  = threadIdx.x;
    const int bh = blockIdx.y;
    const int s0 = blockIdx.x * P2_ROWS;
    const long long base = (long long)bh * NS * ND;

    __shared__ float skv[ND * ND];           // 16 KB
    __shared__ float sq[P2_ROWS * 65];       // 33.3 KB, phi(q/8), padded
    __shared__ float sk1[ND];

    // stage KV + k1
    {
        const float4* src = (const float4*)(KV + (long long)bh * ND * ND);
        #pragma unroll
        for (int i = 0; i < 4; ++i) ((float4*)skv)[t + 256 * i] = src[t + 256 * i];
        if (t < 16) ((float4*)sk1)[t] = ((const float4*)(K1 + bh * ND))[t];
    }
    // stage phi(Q * 1/8), two batches of 4 float4/lane
    {
        const int lrow = t >> 4;
        const int lcol = (t & 15) * 4;
        #pragma unroll
        for (int hb = 0; hb < 2; ++hb) {
            float4 q4[4];
            #pragma unroll
            for (int i = 0; i < 4; ++i) {
                const int r = lrow + 16 * (4 * hb + i);
                q4[i] = *(const float4*)(Qin + base + (long long)(s0 + r) * ND + lcol);
            }
            #pragma unroll
            for (int i = 0; i < 4; ++i) {
                const int r = lrow + 16 * (4 * hb + i);
                sq[r * 65 + lcol + 0] = phi_f(q4[i].x * 0.125f);
                sq[r * 65 + lcol + 1] = phi_f(q4[i].y * 0.125f);
                sq[r * 65 + lcol + 2] = phi_f(q4[i].z * 0.125f);
                sq[r * 65 + lcol + 3] = phi_f(q4[i].w * 0.125f);
            }
        }
    }
    __syncthreads();

    const int r0 = (t >> 3) * 4;             // lane's 4 rows (0..124)
    const int v0 = (t & 7) * 8;              // lane's 8 cols

    float acc[4][8] = {};
    float nacc[4] = {0.f, 0.f, 0.f, 0.f};

    #pragma unroll 4
    for (int d = 0; d < ND; ++d) {
        const float s1 = sk1[d];
        float q[4];
        #pragma unroll
        for (int j = 0; j < 4; ++j) q[j] = sq[(r0 + j) * 65 + d];
        const float4 b0 = *(const float4*)(skv + d * ND + v0);
        const float4 b1 = *(const float4*)(skv + d * ND + v0 + 4);
        const float bv[8] = {b0.x, b0.y, b0.z, b0.w, b1.x, b1.y, b1.z, b1.w};
        #pragma unroll
        for (int j = 0; j < 4; ++j) {
            nacc[j] += q[j] * s1;
            #pragma unroll
            for (int k = 0; k < 8; ++k)
                acc[j][k] += q[j] * bv[k];
        }
    }

    float* outb = Out + base;
    #pragma unroll
    for (int j = 0; j < 4; ++j) {
        const float rn = 1.0f / (nacc[j] + EPSF);
        float4 o0, o1;
        o0.x = acc[j][0] * rn; o0.y = acc[j][1] * rn;
        o0.z = acc[j][2] * rn; o0.w = acc[j][3] * rn;
        o1.x = acc[j][4] * rn; o1.y = acc[j][5] * rn;
        o1.z = acc[j][6] * rn; o1.w = acc[j][7] * rn;
        *(float4*)(outb + (long long)(s0 + r0 + j) * ND + v0)     = o0;
        *(float4*)(outb + (long long)(s0 + r0 + j) * ND + v0 + 4) = o1;
    }
}

extern "C" void kernel_launch(void* const* d_in, const int* in_sizes, int n_in,
                              void* d_out, int out_size, void* d_ws, size_t ws_size,
                              hipStream_t stream)
{
    const float* Q = (const float*)d_in[0];
    const float* K = (const float*)d_in[1];
    const float* V = (const float*)d_in[2];
    const float* M = (const float*)d_in[3];
    float* Out = (float*)d_out;

    const size_t partf = (size_t)NBH * P1_CHUNKS * ND * ND;  // 4,194,304 floats
    const size_t pk1f  = (size_t)NBH * P1_CHUNKS * ND;       //    65,536
    const size_t kvf   = (size_t)NBH * ND * ND;              //   262,144
    const size_t k1f   = (size_t)NBH * ND;                   //     4,096
    const size_t need  = (partf + pk1f + kvf + k1f) * sizeof(float); // ~18.1 MB

    if (ws_size >= need) {
        // atomic-free deterministic path
        float* PKV = (float*)d_ws;
        float* PK1 = PKV + partf;
        float* KVb = PK1 + pk1f;
        float* K1b = KVb + kvf;
        la_pass1<true><<<dim3(P1_CHUNKS, NBH), dim3(256), 0, stream>>>(K, V, M, PKV, PK1);
        la_reduce<<<dim3(NBH), dim3(256), 0, stream>>>(PKV, PK1, KVb, K1b);
        la_pass2<<<dim3(NS / P2_ROWS, NBH), dim3(256), 0, stream>>>(Q, KVb, K1b, Out);
    } else {
        // fallback: coalesced atomics into zeroed KV/K1
        float* KVb = (float*)d_ws;
        float* K1b = KVb + kvf;
        hipMemsetAsync(d_ws, 0, (kvf + k1f) * sizeof(float), stream);
        la_pass1<false><<<dim3(P1_CHUNKS, NBH), dim3(256), 0, stream>>>(K, V, M, KVb, K1b);
        la_pass2<<<dim3(NS / P2_ROWS, NBH), dim3(256), 0, stream>>>(Q, KVb, K1b, Out);
    }
}

// Round 5
// 242.959 us; speedup vs baseline: 2.0583x; 1.0860x over previous
//
#include <hip/hip_runtime.h>

typedef unsigned short ushort_t;
typedef unsigned int uint32;
typedef __bf16 bf16x8 __attribute__((ext_vector_type(8)));
typedef float f32x4 __attribute__((ext_vector_type(4)));

#define NB 4
#define NH 16
#define NS 4096
#define ND 64
#define NBH 64
#define EPSF 1e-6f

#define CH1 16
#define ROWS1 (NS / CH1)          // 256 rows per pass1 block
#define P2R 128
#define LDJ 70                    // ushort row stride (word stride 35 -> <=2-way banks)
#define LDJW 35

__device__ __forceinline__ float phi_f(float x) {
    // elu(x)+1 : x>0 ? x+1 : exp(x)
    return x > 0.0f ? x + 1.0f : __expf(x);
}
__device__ __forceinline__ ushort_t bf16_rn(float x) {
    uint32 u = __float_as_uint(x);
    uint32 r = (u + 0x7FFFu + ((u >> 16) & 1u)) >> 16;
    return (ushort_t)r;
}
__device__ __forceinline__ void split2(float x, ushort_t& h, ushort_t& l) {
    h = bf16_rn(x);
    float hf = __uint_as_float(((uint32)h) << 16);
    l = bf16_rn(x - hf);
}
union FragU { uint32 u[4]; bf16x8 v; };
__device__ __forceinline__ bf16x8 ld_frag(const ushort_t* arr, int widx) {
    const uint32* p = (const uint32*)arr;
    FragU f;
    f.u[0] = p[widx]; f.u[1] = p[widx + 1]; f.u[2] = p[widx + 2]; f.u[3] = p[widx + 3];
    return f.v;
}
__device__ __forceinline__ f32x4 mfma16(bf16x8 a, bf16x8 b, f32x4 c) {
    return __builtin_amdgcn_mfma_f32_16x16x32_bf16(a, b, c, 0, 0, 0);
}

// =====================================================================
// Pass 1: partial KV = phiK^T @ V over a 256-row chunk (+ partial k1).
// Split-fp32 (bf16 hi/lo, 3 MFMA per tile). phiK and V staged TRANSPOSED
// ([d or v][s], k-contiguous) as bf16 hi/lo; row-pair loader packs two
// s-adjacent bf16 per b32 LDS write. 4 waves x (1 M-strip x 4 N-tiles).
// LDS 35 KB -> 4 blocks/CU.
// =====================================================================
template<bool PART>
__global__ __launch_bounds__(256)
void la_pass1(const float* __restrict__ Kin, const float* __restrict__ Vin,
              const float* __restrict__ Min, float* __restrict__ okv,
              float* __restrict__ ok1)
{
    const int t  = threadIdx.x;
    const int cx = blockIdx.x;
    const int bh = blockIdx.y;
    const int bb = bh >> 4;                   // H = 16
    const float* Kb = Kin + (long long)bh * NS * ND;
    const float* Vb = Vin + (long long)bh * NS * ND;
    const float* Mb = Min + (long long)bb * NS;

    __shared__ __align__(16) ushort_t skh[64 * LDJ], skl[64 * LDJ];
    __shared__ __align__(16) ushort_t svh[64 * LDJ], svl[64 * LDJ];

    const int p  = t & 31;                    // staging row-pair (rows 2p, 2p+1)
    const int c0 = (t >> 5) * 8;              // staging cols c0..c0+7
    const int wv = t >> 6;                    // wave id -> d-strip 16*wv
    const int m  = t & 15;
    const int q  = (t & 63) >> 4;
    const int lane = t & 63;

    const f32x4 zf = {0.f, 0.f, 0.f, 0.f};
    f32x4 acc0 = zf, acc1 = zf, acc2 = zf, acc3 = zf;
    float k1loc[8] = {0.f,0.f,0.f,0.f,0.f,0.f,0.f,0.f};

    const int s0 = cx * ROWS1;

    for (int tile = 0; tile < ROWS1 / 64; ++tile) {
        const int rb = s0 + tile * 64;
        __syncthreads();                       // previous tile consumed
        {
            const int r0 = rb + 2 * p;
            const float4 ka = *(const float4*)(Kb + (long long)r0 * ND + c0);
            const float4 kb2 = *(const float4*)(Kb + (long long)r0 * ND + c0 + 4);
            const float4 kc = *(const float4*)(Kb + (long long)(r0 + 1) * ND + c0);
            const float4 kd = *(const float4*)(Kb + (long long)(r0 + 1) * ND + c0 + 4);
            const float4 va = *(const float4*)(Vb + (long long)r0 * ND + c0);
            const float4 vb2 = *(const float4*)(Vb + (long long)r0 * ND + c0 + 4);
            const float4 vc = *(const float4*)(Vb + (long long)(r0 + 1) * ND + c0);
            const float4 vd = *(const float4*)(Vb + (long long)(r0 + 1) * ND + c0 + 4);
            const float m0 = Mb[r0], m1 = Mb[r0 + 1];
            const float kr0[8] = {ka.x,ka.y,ka.z,ka.w,kb2.x,kb2.y,kb2.z,kb2.w};
            const float kr1[8] = {kc.x,kc.y,kc.z,kc.w,kd.x,kd.y,kd.z,kd.w};
            const float vr0[8] = {va.x,va.y,va.z,va.w,vb2.x,vb2.y,vb2.z,vb2.w};
            const float vr1[8] = {vc.x,vc.y,vc.z,vc.w,vd.x,vd.y,vd.z,vd.w};
            #pragma unroll
            for (int i = 0; i < 8; ++i) {
                const float x0 = phi_f(kr0[i]) * m0;
                const float x1 = phi_f(kr1[i]) * m1;
                k1loc[i] += x0 + x1;
                ushort_t h0, l0, h1, l1;
                split2(x0, h0, l0); split2(x1, h1, l1);
                const int widx = (c0 + i) * LDJW + p;      // elem (c0+i)*70 + 2p
                ((uint32*)skh)[widx] = (uint32)h0 | ((uint32)h1 << 16);
                ((uint32*)skl)[widx] = (uint32)l0 | ((uint32)l1 << 16);
                split2(vr0[i], h0, l0); split2(vr1[i], h1, l1);
                ((uint32*)svh)[widx] = (uint32)h0 | ((uint32)h1 << 16);
                ((uint32*)svl)[widx] = (uint32)l0 | ((uint32)l1 << 16);
            }
        }
        __syncthreads();
        #pragma unroll
        for (int ks = 0; ks < 2; ++ks) {
            const int fo = ks * 16 + q * 4;
            const bf16x8 ah = ld_frag(skh, (16 * wv + m) * LDJW + fo);
            const bf16x8 al = ld_frag(skl, (16 * wv + m) * LDJW + fo);
            {
                const bf16x8 fbh = ld_frag(svh, (0 + m) * LDJW + fo);
                const bf16x8 fbl = ld_frag(svl, (0 + m) * LDJW + fo);
                acc0 = mfma16(al, fbh, acc0); acc0 = mfma16(ah, fbl, acc0); acc0 = mfma16(ah, fbh, acc0);
            }
            {
                const bf16x8 fbh = ld_frag(svh, (16 + m) * LDJW + fo);
                const bf16x8 fbl = ld_frag(svl, (16 + m) * LDJW + fo);
                acc1 = mfma16(al, fbh, acc1); acc1 = mfma16(ah, fbl, acc1); acc1 = mfma16(ah, fbh, acc1);
            }
            {
                const bf16x8 fbh = ld_frag(svh, (32 + m) * LDJW + fo);
                const bf16x8 fbl = ld_frag(svl, (32 + m) * LDJW + fo);
                acc2 = mfma16(al, fbh, acc2); acc2 = mfma16(ah, fbl, acc2); acc2 = mfma16(ah, fbh, acc2);
            }
            {
                const bf16x8 fbh = ld_frag(svh, (48 + m) * LDJW + fo);
                const bf16x8 fbl = ld_frag(svl, (48 + m) * LDJW + fo);
                acc3 = mfma16(al, fbh, acc3); acc3 = mfma16(ah, fbl, acc3); acc3 = mfma16(ah, fbh, acc3);
            }
        }
    }

    // ---- store partial KV (D[row=q*4+i within strip][col=16nt+m]) ----
    const int dbase = 16 * wv + q * 4;
    if (PART) {
        float* outp = okv + (long long)(bh * CH1 + cx) * (ND * ND);
        #pragma unroll
        for (int i = 0; i < 4; ++i) {
            outp[(dbase + i) * ND +  0 + m] = acc0[i];
            outp[(dbase + i) * ND + 16 + m] = acc1[i];
            outp[(dbase + i) * ND + 32 + m] = acc2[i];
            outp[(dbase + i) * ND + 48 + m] = acc3[i];
        }
    } else {
        float* outp = okv + (long long)bh * (ND * ND);
        #pragma unroll
        for (int i = 0; i < 4; ++i) {
            atomicAdd(&outp[(dbase + i) * ND +  0 + m], acc0[i]);
            atomicAdd(&outp[(dbase + i) * ND + 16 + m], acc1[i]);
            atomicAdd(&outp[(dbase + i) * ND + 32 + m], acc2[i]);
            atomicAdd(&outp[(dbase + i) * ND + 48 + m], acc3[i]);
        }
    }
    // ---- k1 partial reduce through LDS (stride-33 floats: 2-way banks) ----
    __syncthreads();
    float* red = (float*)skh;                  // 64*33 floats = 8448 B <= 8960 B
    #pragma unroll
    for (int i = 0; i < 8; ++i) red[(c0 + i) * 33 + p] = k1loc[i];
    __syncthreads();
    if (t < 64) {
        float s = 0.f;
        #pragma unroll
        for (int pp = 0; pp < 32; ++pp) s += red[t * 33 + pp];
        if (PART) ok1[(bh * CH1 + cx) * ND + t] = s;
        else      atomicAdd(&ok1[bh * ND + t], s);
    }
}

// =====================================================================
// Reduce: KV[bh] = sum of CH1 partial tiles; K1[bh] = sum of partials.
// =====================================================================
__global__ __launch_bounds__(256)
void la_reduce(const float* __restrict__ pkv, const float* __restrict__ pk1,
               float* __restrict__ kv, float* __restrict__ k1)
{
    const int t = threadIdx.x;
    const int bh = blockIdx.x;
    const float4* src = (const float4*)(pkv + (long long)bh * CH1 * ND * ND);
    float4 a[4];
    #pragma unroll
    for (int i = 0; i < 4; ++i) { a[i].x = 0.f; a[i].y = 0.f; a[i].z = 0.f; a[i].w = 0.f; }
    for (int c = 0; c < CH1; ++c) {
        #pragma unroll
        for (int i = 0; i < 4; ++i) {
            const float4 v = src[c * 1024 + t + 256 * i];
            a[i].x += v.x; a[i].y += v.y; a[i].z += v.z; a[i].w += v.w;
        }
    }
    float4* dst = (float4*)(kv + (long long)bh * ND * ND);
    #pragma unroll
    for (int i = 0; i < 4; ++i) dst[t + 256 * i] = a[i];
    if (t < ND) {
        float s = 0.f;
        for (int c = 0; c < CH1; ++c) s += pk1[(bh * CH1 + c) * ND + t];
        k1[bh * ND + t] = s;
    }
}

// =====================================================================
// Pass 2: out = (phiQ @ [KV | k1]) / norm, split-fp32 MFMA.
// A = phi(q/8) row-major (k=d contiguous -> no transpose), B = KV^T with
// k1 appended as row 64 (n-tile 4 col 0 = normalizer), rows 65..79 zero.
// Normalizer broadcast via __shfl from lane (quad*16). LDS 58 KB.
// =====================================================================
__global__ __launch_bounds__(256)
void la_pass2(const float* __restrict__ Qin, const float* __restrict__ KVin,
              const float* __restrict__ K1in, float* __restrict__ Out)
{
    const int t  = threadIdx.x;
    const int bh = blockIdx.y;
    const int s0 = blockIdx.x * P2R;
    const long long base = (long long)bh * NS * ND;

    __shared__ __align__(16) ushort_t sAh[P2R * LDJ], sAl[P2R * LDJ];  // 17.5 KB each
    __shared__ __align__(16) ushort_t sBh[80 * LDJ],  sBl[80 * LDJ];   // 10.9 KB each

    // ---- stage B: KV^T + k1 row + zero rows ----
    {
        const float* KVb = KVin + (long long)bh * ND * ND;
        const int d  = t >> 4;
        const int v4 = (t & 15) * 4;
        #pragma unroll
        for (int it = 0; it < 4; ++it) {
            const int dd = d + 16 * it;
            const float4 kv = *(const float4*)(KVb + dd * ND + v4);
            const float vals[4] = {kv.x, kv.y, kv.z, kv.w};
            #pragma unroll
            for (int i = 0; i < 4; ++i) {
                ushort_t h, l; split2(vals[i], h, l);
                sBh[(v4 + i) * LDJ + dd] = h;
                sBl[(v4 + i) * LDJ + dd] = l;
            }
        }
        if (t < 64) {
            ushort_t h, l; split2(K1in[bh * ND + t], h, l);
            sBh[64 * LDJ + t] = h; sBl[64 * LDJ + t] = l;
        }
        for (int z = t; z < 15 * 64; z += 256) {
            const int n  = 65 + (z >> 6);
            const int dd = z & 63;
            sBh[n * LDJ + dd] = 0; sBl[n * LDJ + dd] = 0;
        }
    }
    // ---- stage A: phi(q/8) hi/lo, row-major, b32 pair writes ----
    {
        const int lr = t >> 4;
        const int lc = (t & 15) * 4;
        #pragma unroll
        for (int it = 0; it < 8; ++it) {
            const int r = lr + 16 * it;
            const float4 q4 = *(const float4*)(Qin + base + (long long)(s0 + r) * ND + lc);
            const float xs[4] = {q4.x, q4.y, q4.z, q4.w};
            ushort_t h[4], l[4];
            #pragma unroll
            for (int i = 0; i < 4; ++i) split2(phi_f(xs[i] * 0.125f), h[i], l[i]);
            const int w0 = (r * LDJ + lc) >> 1;
            ((uint32*)sAh)[w0]     = (uint32)h[0] | ((uint32)h[1] << 16);
            ((uint32*)sAh)[w0 + 1] = (uint32)h[2] | ((uint32)h[3] << 16);
            ((uint32*)sAl)[w0]     = (uint32)l[0] | ((uint32)l[1] << 16);
            ((uint32*)sAl)[w0 + 1] = (uint32)l[2] | ((uint32)l[3] << 16);
        }
    }
    __syncthreads();

    const int wv = t >> 6;
    const int m  = t & 15;
    const int q  = (t & 63) >> 4;
    const int lane = t & 63;

    const f32x4 zf = {0.f, 0.f, 0.f, 0.f};
    f32x4 acc[2][5];
    #pragma unroll
    for (int a = 0; a < 2; ++a)
        #pragma unroll
        for (int b = 0; b < 5; ++b) acc[a][b] = zf;

    #pragma unroll
    for (int ks = 0; ks < 2; ++ks) {
        const int fo = ks * 16 + q * 4;
        const bf16x8 a0h = ld_frag(sAh, (16 * (2 * wv + 0) + m) * LDJW + fo);
        const bf16x8 a0l = ld_frag(sAl, (16 * (2 * wv + 0) + m) * LDJW + fo);
        const bf16x8 a1h = ld_frag(sAh, (16 * (2 * wv + 1) + m) * LDJW + fo);
        const bf16x8 a1l = ld_frag(sAl, (16 * (2 * wv + 1) + m) * LDJW + fo);
        #pragma unroll
        for (int nt = 0; nt < 5; ++nt) {
            const bf16x8 fbh = ld_frag(sBh, (16 * nt + m) * LDJW + fo);
            const bf16x8 fbl = ld_frag(sBl, (16 * nt + m) * LDJW + fo);
            acc[0][nt] = mfma16(a0l, fbh, acc[0][nt]);
            acc[0][nt] = mfma16(a0h, fbl, acc[0][nt]);
            acc[0][nt] = mfma16(a0h, fbh, acc[0][nt]);
            acc[1][nt] = mfma16(a1l, fbh, acc[1][nt]);
            acc[1][nt] = mfma16(a1h, fbl, acc[1][nt]);
            acc[1][nt] = mfma16(a1h, fbh, acc[1][nt]);
        }
    }

    // ---- epilogue: normalizer in acc[*][4] col 0 (lane m==0) ----
    float* outb = Out + base;
    #pragma unroll
    for (int mtl = 0; mtl < 2; ++mtl) {
        const int rbase = s0 + 16 * (2 * wv + mtl) + q * 4;
        #pragma unroll
        for (int i = 0; i < 4; ++i) {
            const float nv = __shfl(acc[mtl][4][i], lane & 48, 64);
            const float rn = 1.0f / (nv + EPSF);
            const long long ro = (long long)(rbase + i) * ND;
            outb[ro +  0 + m] = acc[mtl][0][i] * rn;
            outb[ro + 16 + m] = acc[mtl][1][i] * rn;
            outb[ro + 32 + m] = acc[mtl][2][i] * rn;
            outb[ro + 48 + m] = acc[mtl][3][i] * rn;
        }
    }
}

extern "C" void kernel_launch(void* const* d_in, const int* in_sizes, int n_in,
                              void* d_out, int out_size, void* d_ws, size_t ws_size,
                              hipStream_t stream)
{
    const float* Q = (const float*)d_in[0];
    const float* K = (const float*)d_in[1];
    const float* V = (const float*)d_in[2];
    const float* M = (const float*)d_in[3];
    float* Out = (float*)d_out;

    const size_t partf = (size_t)NBH * CH1 * ND * ND;   // 4,194,304 floats
    const size_t pk1f  = (size_t)NBH * CH1 * ND;        //    65,536
    const size_t kvf   = (size_t)NBH * ND * ND;         //   262,144
    const size_t k1f   = (size_t)NBH * ND;              //     4,096
    const size_t need  = (partf + pk1f + kvf + k1f) * sizeof(float); // ~18.1 MB

    if (ws_size >= need) {
        float* PKV = (float*)d_ws;
        float* PK1 = PKV + partf;
        float* KVb = PK1 + pk1f;
        float* K1b = KVb + kvf;
        la_pass1<true><<<dim3(CH1, NBH), dim3(256), 0, stream>>>(K, V, M, PKV, PK1);
        la_reduce<<<dim3(NBH), dim3(256), 0, stream>>>(PKV, PK1, KVb, K1b);
        la_pass2<<<dim3(NS / P2R, NBH), dim3(256), 0, stream>>>(Q, KVb, K1b, Out);
    } else {
        float* KVb = (float*)d_ws;
        float* K1b = KVb + kvf;
        hipMemsetAsync(d_ws, 0, (kvf + k1f) * sizeof(float), stream);
        la_pass1<false><<<dim3(CH1, NBH), dim3(256), 0, stream>>>(K, V, M, KVb, K1b);
        la_pass2<<<dim3(NS / P2R, NBH), dim3(256), 0, stream>>>(Q, KVb, K1b, Out);
    }
}